// Round 3
// baseline (457.970 us; speedup 1.0000x reference)
//
#include <hip/hip_runtime.h>
#include <math.h>

#define D_MODEL 4096
#define NE 64                 // experts
#define TPB 64                // tokens per block (lane = token)
#define KT 256                // k staged per step
#define NSTEPS (D_MODEL / KT) // 16
#define ROW4 65               // float4s per padded LDS row (odd -> conflict-free)

typedef float f16v __attribute__((ext_vector_type(16)));

__global__ __launch_bounds__(1024) void router_kernel(
    const float* __restrict__ x, const float* __restrict__ W,
    const float* __restrict__ b, float* __restrict__ out, int T)
{
    // union: x double-buffer (2*64*260 = 33280 f) / reduction tree (8*64*68 = 34816 f)
    __shared__ float lds[35840];   // 140 KB

    const int tid  = threadIdx.x;
    const int wv   = __builtin_amdgcn_readfirstlane(tid >> 6); // wave 0..15 = k-slice
    const int lane = tid & 63;                                 // token-in-block
    const int tok0 = blockIdx.x * TPB;

    // staging map: thread (r, c) moves x[tok0+r][c*4 + q*64] each step
    const int r = tid >> 4, c = tid & 15;
    const float* gx = x + (size_t)(tok0 + r) * D_MODEL + c * 4;
    float4* const xt4 = (float4*)lds;

    float acc[NE];
#pragma unroll
    for (int e = 0; e < NE; e++) acc[e] = 0.f;

    // prologue: stage step 0 into buffer 0
#pragma unroll
    for (int q = 0; q < 4; q++)
        xt4[r * ROW4 + q * 16 + c] = *(const float4*)(gx + q * 64);
    __syncthreads();

    for (int s = 0; s < NSTEPS; s++) {
        const bool more = (s + 1 < NSTEPS);
        float4 n0, n1, n2, n3;
        if (more) {   // prefetch next chunk early; latency hides under 1024 FMAs
            const float* g = gx + (size_t)(s + 1) * KT;
            n0 = *(const float4*)(g);
            n1 = *(const float4*)(g + 64);
            n2 = *(const float4*)(g + 128);
            n3 = *(const float4*)(g + 192);
        }
        // this wave's 16-k x fragment of own token row (4x ds_read_b128, reused 64x)
        const float4* xb = xt4 + (s & 1) * (TPB * ROW4) + lane * ROW4 + wv * 4;
        const float4 xa = xb[0], xc = xb[1], xd = xb[2], xe = xb[3];

        const float* Wp = W + s * KT + wv * 16;   // wave-uniform -> scalar loads
#pragma unroll
        for (int e = 0; e < NE; e++) {
            f16v w = *(const f16v*)(Wp + (size_t)e * D_MODEL); // s_load_dwordx16
            float a = acc[e];
            a = fmaf(w[0],  xa.x, a); a = fmaf(w[1],  xa.y, a);
            a = fmaf(w[2],  xa.z, a); a = fmaf(w[3],  xa.w, a);
            a = fmaf(w[4],  xc.x, a); a = fmaf(w[5],  xc.y, a);
            a = fmaf(w[6],  xc.z, a); a = fmaf(w[7],  xc.w, a);
            a = fmaf(w[8],  xd.x, a); a = fmaf(w[9],  xd.y, a);
            a = fmaf(w[10], xd.z, a); a = fmaf(w[11], xd.w, a);
            a = fmaf(w[12], xe.x, a); a = fmaf(w[13], xe.y, a);
            a = fmaf(w[14], xe.z, a); a = fmaf(w[15], xe.w, a);
            acc[e] = a;
        }
        if (more) {   // write prefetched chunk to the other buffer
            float4* d = xt4 + ((s + 1) & 1) * (TPB * ROW4) + r * ROW4 + c;
            d[0]  = n0;
            d[16] = n1;
            d[32] = n2;
            d[48] = n3;
        }
        __syncthreads();
    }

    // ---- tree reduction over the 16 k-slice waves (reuses lds) ----
    float4* red4 = (float4*)lds;   // [slot][64 tok][17 float4]
#pragma unroll
    for (int half = 8; half >= 1; half >>= 1) {
        if (wv >= half && wv < 2 * half) {
            float4* dst = red4 + ((wv - half) * 64 + lane) * 17;
#pragma unroll
            for (int j = 0; j < 16; j++)
                dst[j] = make_float4(acc[4*j], acc[4*j+1], acc[4*j+2], acc[4*j+3]);
        }
        __syncthreads();
        if (wv < half) {
            const float4* sp = red4 + (wv * 64 + lane) * 17;
#pragma unroll
            for (int j = 0; j < 16; j++) {
                float4 v = sp[j];
                acc[4*j]   += v.x; acc[4*j+1] += v.y;
                acc[4*j+2] += v.z; acc[4*j+3] += v.w;
            }
        }
        __syncthreads();
    }

    // ---- wave 0: bias + top-2 + softmax + store ----
    if (wv == 0) {
        float v0 = -INFINITY, v1 = -INFINITY;
        int i0 = 0, i1 = 0;
#pragma unroll
        for (int e = 0; e < NE; e++) {
            const float v = acc[e] + b[e];
            if (v > v0)      { v1 = v0; i1 = i0; v0 = v; i0 = e; }
            else if (v > v1) { v1 = v;  i1 = e; }
        }
        const float e1 = expf(v1 - v0);      // v0 >= v1
        const float w0 = 1.f / (1.f + e1);
        const int tok = tok0 + lane;
        out[tok * 2 + 0] = w0;
        out[tok * 2 + 1] = e1 * w0;
        float* oi = out + (size_t)T * 2;     // indices chunk (float-cast)
        oi[tok * 2 + 0] = (float)i0;
        oi[tok * 2 + 1] = (float)i1;
    }
}

extern "C" void kernel_launch(void* const* d_in, const int* in_sizes, int n_in,
                              void* d_out, int out_size, void* d_ws, size_t ws_size,
                              hipStream_t stream) {
    const float* x = (const float*)d_in[0];
    const float* W = (const float*)d_in[1];
    const float* b = (const float*)d_in[2];
    float* out = (float*)d_out;
    const int T = in_sizes[0] / D_MODEL;     // 16384 tokens
    const int grid = T / TPB;                // 256 blocks -> 1 per CU
    hipLaunchKernelGGL(router_kernel, dim3(grid), dim3(1024), 0, stream,
                       x, W, b, out, T);
}

// Round 4
// 101.808 us; speedup vs baseline: 4.4984x; 4.4984x over previous
//
#include <hip/hip_runtime.h>
#include <math.h>

#define D_MODEL 4096
#define NE 64
#define TPB 64                 // tokens per block
#define KT 128                 // k per staged step
#define NSTEPS (D_MODEL / KT)  // 32

typedef __attribute__((ext_vector_type(8))) short short8;
typedef __attribute__((ext_vector_type(16))) float f32x16;

// LDS per buffer (shorts): A_hi[8c][2mt][64 slot][8] = 8192 | A_lo +8192
//                          W_hi +16384 | W_lo +24576   -> 32768 shorts = 64 KB
// two buffers = 128 KB; epilogue reuses the same memory.

__device__ __forceinline__ void split8(const float4& a, const float4& c,
                                       short8& h8, short8& l8) {
    float vv[8] = {a.x, a.y, a.z, a.w, c.x, c.y, c.z, c.w};
#pragma unroll
    for (int j = 0; j < 8; j++) {
        unsigned u = __float_as_uint(vv[j]);
        unsigned r = u + 0x7fffu + ((u >> 16) & 1u);      // bf16 RN (no NaN inputs)
        float hf = __uint_as_float(r & 0xffff0000u);
        float lo = vv[j] - hf;                             // exact
        unsigned u2 = __float_as_uint(lo);
        unsigned r2 = u2 + 0x7fffu + ((u2 >> 16) & 1u);
        h8[j] = (short)(r >> 16);
        l8[j] = (short)(r2 >> 16);
    }
}

__global__ __launch_bounds__(1024, 4) void router_kernel(
    const float* __restrict__ x, const float* __restrict__ W,
    const float* __restrict__ b, float* __restrict__ out, int T)
{
    __shared__ short smem[65536];   // 128 KB

    const int tid  = threadIdx.x;
    const int wv   = __builtin_amdgcn_readfirstlane(tid >> 6); // 0..15
    const int lane = tid & 63;
    const int tok0 = blockIdx.x * TPB;

    // ---- staging identity: row(=tok/exp) fast across lanes -> conflict-free LDS writes
    const int st_row = tid & 63;          // token index == expert index
    const int st_kc  = tid >> 6;          // 0..15 : which 8-k group of the 128-k step
    const int st_c   = st_kc >> 1;        // 16-k chunk 0..7
    const int st_h   = st_kc & 1;         // k-half within chunk
    const int st_tn  = st_row >> 5;       // mt for A, nt for W (same value)
    const int st_off = (st_c * 2 + st_tn) * 512 + (st_h * 32 + (st_row & 31)) * 8;
    const float* gx = x + (size_t)(tok0 + st_row) * D_MODEL + st_kc * 8;
    const float* gw = W + (size_t)st_row * D_MODEL + st_kc * 8;

    // ---- compute identity: wave = (mt, c)
    const int mt = wv & 1;                // 32-token group
    const int c  = wv >> 1;               // K-slice / chunk 0..7
    const int fA  = (c * 2 + mt) * 512 + lane * 8;   // shorts, into A slabs
    const int fB0 = (c * 2 + 0)  * 512 + lane * 8;   // into W slabs
    const int fB1 = (c * 2 + 1)  * 512 + lane * 8;

    f32x16 acc[2];
#pragma unroll
    for (int e = 0; e < 16; e++) { acc[0][e] = 0.f; acc[1][e] = 0.f; }

    // ---- prologue: stage step 0 into buffer 0
    {
        float4 x0 = *(const float4*)(gx), x1 = *(const float4*)(gx + 4);
        float4 w0 = *(const float4*)(gw), w1 = *(const float4*)(gw + 4);
        short8 h8, l8;
        split8(x0, x1, h8, l8);
        *(short8*)(smem + st_off)          = h8;
        *(short8*)(smem + 8192  + st_off)  = l8;
        split8(w0, w1, h8, l8);
        *(short8*)(smem + 16384 + st_off)  = h8;
        *(short8*)(smem + 24576 + st_off)  = l8;
    }
    __syncthreads();

    for (int s = 0; s < NSTEPS; s++) {
        float4 px0, px1, pw0, pw1;
        const bool more = (s + 1 < NSTEPS);
        if (more) {
            const float* gx2 = gx + (size_t)(s + 1) * KT;
            const float* gw2 = gw + (size_t)(s + 1) * KT;
            px0 = *(const float4*)(gx2); px1 = *(const float4*)(gx2 + 4);
            pw0 = *(const float4*)(gw2); pw1 = *(const float4*)(gw2 + 4);
        }
        const short* buf = smem + (s & 1) * 32768;
        short8 Ah  = *(const short8*)(buf + fA);
        short8 Al  = *(const short8*)(buf + 8192  + fA);
        short8 B0h = *(const short8*)(buf + 16384 + fB0);
        short8 B0l = *(const short8*)(buf + 24576 + fB0);
        short8 B1h = *(const short8*)(buf + 16384 + fB1);
        short8 B1l = *(const short8*)(buf + 24576 + fB1);
        acc[0] = __builtin_amdgcn_mfma_f32_32x32x16_bf16(Ah, B0h, acc[0], 0, 0, 0);
        acc[0] = __builtin_amdgcn_mfma_f32_32x32x16_bf16(Ah, B0l, acc[0], 0, 0, 0);
        acc[0] = __builtin_amdgcn_mfma_f32_32x32x16_bf16(Al, B0h, acc[0], 0, 0, 0);
        acc[0] = __builtin_amdgcn_mfma_f32_32x32x16_bf16(Al, B0l, acc[0], 0, 0, 0);
        acc[1] = __builtin_amdgcn_mfma_f32_32x32x16_bf16(Ah, B1h, acc[1], 0, 0, 0);
        acc[1] = __builtin_amdgcn_mfma_f32_32x32x16_bf16(Ah, B1l, acc[1], 0, 0, 0);
        acc[1] = __builtin_amdgcn_mfma_f32_32x32x16_bf16(Al, B1h, acc[1], 0, 0, 0);
        acc[1] = __builtin_amdgcn_mfma_f32_32x32x16_bf16(Al, B1l, acc[1], 0, 0, 0);
        if (more) {
            short* nb = smem + ((s + 1) & 1) * 32768;
            short8 h8, l8;
            split8(px0, px1, h8, l8);
            *(short8*)(nb + st_off)         = h8;
            *(short8*)(nb + 8192  + st_off) = l8;
            split8(pw0, pw1, h8, l8);
            *(short8*)(nb + 16384 + st_off) = h8;
            *(short8*)(nb + 24576 + st_off) = l8;
        }
        __syncthreads();
    }

    // ---- reduce the 8 K-slices (rotate-swizzled slabs: conflict-free, static idx)
    float* red = (float*)smem;   // [mt(2)][src(7)][lane(64)][32]
    if (c > 0) {
        float* sl = red + (size_t)((mt * 7 + (c - 1)) * 64 + lane) * 32;
#pragma unroll
        for (int q = 0; q < 8; q++) {           // data quad q -> slot (q+lane)&7
            const int nt = q >> 2, rg = (q & 3) * 4;
            float4 v = make_float4(acc[nt][rg], acc[nt][rg+1], acc[nt][rg+2], acc[nt][rg+3]);
            *(float4*)(sl + ((q + lane) & 7) * 4 + (q >> 2) * 0) = v;  // slot*4 floats
        }
    }
    __syncthreads();
    if (c == 0) {
#pragma unroll
        for (int src = 0; src < 7; src++) {
            const float* sl = red + (size_t)((mt * 7 + src) * 64 + lane) * 32;
#pragma unroll
            for (int q = 0; q < 8; q++) {
                const int nt = q >> 2, rg = (q & 3) * 4;
                float4 v = *(const float4*)(sl + ((q + lane) & 7) * 4);
                acc[nt][rg]   += v.x; acc[nt][rg+1] += v.y;
                acc[nt][rg+2] += v.z; acc[nt][rg+3] += v.w;
            }
        }
    }
    __syncthreads();

    // ---- logits (+bias) to LDS [64 tok][68]
    float* lg = (float*)smem;
    if (c == 0) {
        const int h = lane >> 5, c31 = lane & 31;
        const float bb0 = b[c31], bb1 = b[32 + c31];
#pragma unroll
        for (int nt = 0; nt < 2; nt++) {
#pragma unroll
            for (int e = 0; e < 16; e++) {
                const int row = (e & 3) + 8 * (e >> 2) + 4 * h;   // token within 32
                const int ex  = nt * 32 + c31;
                lg[(mt * 32 + row) * 68 + ex] = acc[nt][e] + (nt ? bb1 : bb0);
            }
        }
    }
    __syncthreads();

    // ---- wave 0: top-2 + softmax + store (lane = token)
    if (wv == 0) {
        const float4* rowp = (const float4*)(lg + lane * 68);
        float v0 = -INFINITY, v1 = -INFINITY;
        int i0 = 0, i1 = 0;
#pragma unroll
        for (int q = 0; q < 16; q++) {
            float4 v4 = rowp[q];
            float vs[4] = {v4.x, v4.y, v4.z, v4.w};
#pragma unroll
            for (int j = 0; j < 4; j++) {
                const int e = q * 4 + j;
                const float v = vs[j];
                if (v > v0)      { v1 = v0; i1 = i0; v0 = v; i0 = e; }
                else if (v > v1) { v1 = v;  i1 = e; }
            }
        }
        const float e1 = expf(v1 - v0);     // v0 >= v1
        const float w0 = 1.f / (1.f + e1);
        const int tok = tok0 + lane;
        out[tok * 2 + 0] = w0;
        out[tok * 2 + 1] = e1 * w0;
        float* oi = out + (size_t)T * 2;    // indices chunk (float-cast)
        oi[tok * 2 + 0] = (float)i0;
        oi[tok * 2 + 1] = (float)i1;
    }
}

extern "C" void kernel_launch(void* const* d_in, const int* in_sizes, int n_in,
                              void* d_out, int out_size, void* d_ws, size_t ws_size,
                              hipStream_t stream) {
    const float* x = (const float*)d_in[0];
    const float* W = (const float*)d_in[1];
    const float* b = (const float*)d_in[2];
    float* out = (float*)d_out;
    const int T = in_sizes[0] / D_MODEL;     // 16384 tokens
    const int grid = T / TPB;                // 256 blocks -> 1 per CU
    hipLaunchKernelGGL(router_kernel, dim3(grid), dim3(1024), 0, stream,
                       x, W, b, out, T);
}

// Round 5
// 79.833 us; speedup vs baseline: 5.7366x; 1.2752x over previous
//
#include <hip/hip_runtime.h>
#include <math.h>

#define D_MODEL 4096
#define NE 64
#define TPB 32                  // tokens per block (one 32x32 MFMA tile)
#define KT 128                  // k per staged step
#define NSTEPS (D_MODEL / KT)   // 32
#define WS_SHORTS (256 * 2 * 64 * 8)   // 262144 shorts per (hi|lo) region

typedef __attribute__((ext_vector_type(8))) short short8;
typedef __attribute__((ext_vector_type(16))) float f32x16;

__device__ __forceinline__ void split8(const float4& a, const float4& c,
                                       short8& h8, short8& l8) {
    float vv[8] = {a.x, a.y, a.z, a.w, c.x, c.y, c.z, c.w};
#pragma unroll
    for (int j = 0; j < 8; j++) {
        float v = vv[j];
        unsigned u = __float_as_uint(v);
        unsigned r = u + 0x7fffu + ((u >> 16) & 1u);   // bf16 RN (inputs finite)
        float hf = __uint_as_float(r & 0xffff0000u);
        float lo = v - hf;                              // exact
        unsigned u2 = __float_as_uint(lo);
        unsigned r2 = u2 + 0x7fffu + ((u2 >> 16) & 1u);
        h8[j] = (short)(r >> 16);
        l8[j] = (short)(r2 >> 16);
    }
}

// Pre-split W (fp32 [64][4096]) -> ws bf16 hi/lo, fragment-linear:
// hi[((ck*2+nt)*64 + l)*8 + j] = bf16hi(W[nt*32+(l&31)][ck*16+(l>>5)*8+j]), lo at +WS_SHORTS
__global__ void wsplit_kernel(const float* __restrict__ W, short* __restrict__ wsp) {
    const int ck = blockIdx.x;          // 0..255
    const int t  = threadIdx.x;         // 0..127
    const int nt = t >> 6, l = t & 63;
    const int e  = nt * 32 + (l & 31);
    const int k  = ck * 16 + (l >> 5) * 8;
    const float* wp = W + (size_t)e * D_MODEL + k;
    float4 a = *(const float4*)wp, c = *(const float4*)(wp + 4);
    short8 h8, l8;
    split8(a, c, h8, l8);
    const size_t off = ((size_t)(ck * 2 + nt) * 64 + l) * 8;
    *(short8*)(wsp + off)             = h8;
    *(short8*)(wsp + WS_SHORTS + off) = l8;
}

template<bool PRE>
__global__ __launch_bounds__(512, 4) void router_kernel(
    const float* __restrict__ x, const float* __restrict__ W,
    const short* __restrict__ wsp, const float* __restrict__ b,
    float* __restrict__ out, int T)
{
    // 32 KB: x dbuf 2 x (hi 4096 + lo 4096 shorts); epilogue reuses as float
    __shared__ short smem[16384];

    const int tid  = threadIdx.x;
    const int wv   = __builtin_amdgcn_readfirstlane(tid >> 6); // 0..7 = k-chunk slice
    const int lane = tid & 63;
    const int tok0 = blockIdx.x * TPB;

    // staging map: thread t -> row = t>>4 (0..31), kc = t&15 (8 floats each)
    const int st_row = tid >> 4, st_kc = tid & 15;
    const int st_ck = st_kc >> 1, st_h = st_kc & 1;
    const float* gx = x + (size_t)(tok0 + st_row) * D_MODEL + st_kc * 8;
    const int st_off = st_ck * 512 + st_h * 256 + st_row * 8;   // shorts, hi slab

    // compute-side fragment offsets (shorts within a buffer)
    const int fA = wv * 512 + (lane >> 5) * 256 + (lane & 31) * 8;

    f32x16 acc[2];
#pragma unroll
    for (int e = 0; e < 16; e++) { acc[0][e] = 0.f; acc[1][e] = 0.f; }

    // ---- prologue: stage step 0, load W frags for step 0
    {
        float4 a = *(const float4*)gx, c = *(const float4*)(gx + 4);
        short8 h8, l8;
        split8(a, c, h8, l8);
        *(short8*)(smem + st_off)        = h8;
        *(short8*)(smem + 4096 + st_off) = l8;
    }
    short8 B0h, B0l, B1h, B1l;
    if (PRE) {
        const size_t ck0 = (size_t)(0 * 8 + wv);
        B0h = *(const short8*)(wsp + ((ck0 * 2 + 0) * 64 + lane) * 8);
        B1h = *(const short8*)(wsp + ((ck0 * 2 + 1) * 64 + lane) * 8);
        B0l = *(const short8*)(wsp + WS_SHORTS + ((ck0 * 2 + 0) * 64 + lane) * 8);
        B1l = *(const short8*)(wsp + WS_SHORTS + ((ck0 * 2 + 1) * 64 + lane) * 8);
    } else {
        const int k0 = wv * 16 + (lane >> 5) * 8;
        const float* w0 = W + (size_t)(0 * 32 + (lane & 31)) * D_MODEL + k0;
        const float* w1 = W + (size_t)(1 * 32 + (lane & 31)) * D_MODEL + k0;
        split8(*(const float4*)w0, *(const float4*)(w0 + 4), B0h, B0l);
        split8(*(const float4*)w1, *(const float4*)(w1 + 4), B1h, B1l);
    }
    __syncthreads();

    for (int s = 0; s < NSTEPS; s++) {
        const bool more = (s + 1 < NSTEPS);
        float4 nx0, nx1, nw00, nw01, nw10, nw11;
        short8 nB0h, nB0l, nB1h, nB1l;
        if (more) {   // prefetch step s+1: x stage chunk + my W fragments
            const float* g = gx + (size_t)(s + 1) * KT;
            nx0 = *(const float4*)g;
            nx1 = *(const float4*)(g + 4);
            if (PRE) {
                const size_t ck = (size_t)((s + 1) * 8 + wv);
                nB0h = *(const short8*)(wsp + ((ck * 2 + 0) * 64 + lane) * 8);
                nB1h = *(const short8*)(wsp + ((ck * 2 + 1) * 64 + lane) * 8);
                nB0l = *(const short8*)(wsp + WS_SHORTS + ((ck * 2 + 0) * 64 + lane) * 8);
                nB1l = *(const short8*)(wsp + WS_SHORTS + ((ck * 2 + 1) * 64 + lane) * 8);
            } else {
                const int k0 = (s + 1) * KT + wv * 16 + (lane >> 5) * 8;
                const float* w0 = W + (size_t)(lane & 31) * D_MODEL + k0;
                const float* w1 = W + (size_t)(32 + (lane & 31)) * D_MODEL + k0;
                nw00 = *(const float4*)w0; nw01 = *(const float4*)(w0 + 4);
                nw10 = *(const float4*)w1; nw11 = *(const float4*)(w1 + 4);
            }
        }
        const short* buf = smem + (s & 1) * 8192;
        short8 Ah = *(const short8*)(buf + fA);
        short8 Al = *(const short8*)(buf + 4096 + fA);
        acc[0] = __builtin_amdgcn_mfma_f32_32x32x16_bf16(Ah, B0h, acc[0], 0, 0, 0);
        acc[0] = __builtin_amdgcn_mfma_f32_32x32x16_bf16(Ah, B0l, acc[0], 0, 0, 0);
        acc[0] = __builtin_amdgcn_mfma_f32_32x32x16_bf16(Al, B0h, acc[0], 0, 0, 0);
        acc[0] = __builtin_amdgcn_mfma_f32_32x32x16_bf16(Al, B0l, acc[0], 0, 0, 0);
        acc[1] = __builtin_amdgcn_mfma_f32_32x32x16_bf16(Ah, B1h, acc[1], 0, 0, 0);
        acc[1] = __builtin_amdgcn_mfma_f32_32x32x16_bf16(Ah, B1l, acc[1], 0, 0, 0);
        acc[1] = __builtin_amdgcn_mfma_f32_32x32x16_bf16(Al, B1h, acc[1], 0, 0, 0);
        acc[1] = __builtin_amdgcn_mfma_f32_32x32x16_bf16(Al, B1l, acc[1], 0, 0, 0);
        if (more) {
            short* nb = smem + ((s + 1) & 1) * 8192;
            short8 h8, l8;
            split8(nx0, nx1, h8, l8);
            *(short8*)(nb + st_off)        = h8;
            *(short8*)(nb + 4096 + st_off) = l8;
            if (PRE) {
                B0h = nB0h; B0l = nB0l; B1h = nB1h; B1l = nB1l;
            } else {
                split8(nw00, nw01, B0h, B0l);
                split8(nw10, nw11, B1h, B1l);
            }
        }
        __syncthreads();
    }

    // ---- 3-round tree reduction over the 8 k-slice waves (32 KB LDS reuse)
    float* red = (float*)smem;
    auto store_slab = [&](int slab) {
        float* sl = red + ((size_t)slab * 64 + lane) * 32;
#pragma unroll
        for (int q = 0; q < 8; q++) {   // quad q -> rotated slot (conflict-dodge)
            const int nt = q >> 2, rg = (q & 3) * 4;
            *(float4*)(sl + ((q + lane) & 7) * 4) =
                make_float4(acc[nt][rg], acc[nt][rg+1], acc[nt][rg+2], acc[nt][rg+3]);
        }
    };
    auto add_slab = [&](int slab) {
        const float* sl = red + ((size_t)slab * 64 + lane) * 32;
#pragma unroll
        for (int q = 0; q < 8; q++) {
            const int nt = q >> 2, rg = (q & 3) * 4;
            float4 v = *(const float4*)(sl + ((q + lane) & 7) * 4);
            acc[nt][rg] += v.x; acc[nt][rg+1] += v.y;
            acc[nt][rg+2] += v.z; acc[nt][rg+3] += v.w;
        }
    };
    if (wv >= 4) store_slab(wv - 4);
    __syncthreads();
    if (wv < 4) add_slab(wv);
    __syncthreads();
    if (wv == 2 || wv == 3) store_slab(wv - 2);
    __syncthreads();
    if (wv < 2) add_slab(wv);
    __syncthreads();
    if (wv == 1) store_slab(0);
    __syncthreads();
    if (wv == 0) add_slab(0);
    __syncthreads();

    // ---- wave 0: logits(+bias) -> LDS [32 tok][68]
    float* lg = (float*)smem;
    if (wv == 0) {
        const int h = lane >> 5, c31 = lane & 31;
        const float bb0 = b[c31], bb1 = b[32 + c31];
#pragma unroll
        for (int nt = 0; nt < 2; nt++) {
#pragma unroll
            for (int e = 0; e < 16; e++) {
                const int row = (e & 3) + 8 * (e >> 2) + 4 * h;  // token in tile
                lg[row * 68 + nt * 32 + c31] = acc[nt][e] + (nt ? bb1 : bb0);
            }
        }
    }
    __syncthreads();

    // ---- top-2 + softmax + store (thread t = token)
    if (tid < TPB) {
        const float4* rowp = (const float4*)(lg + tid * 68);
        float v0 = -INFINITY, v1 = -INFINITY;
        int i0 = 0, i1 = 0;
#pragma unroll
        for (int q = 0; q < 16; q++) {
            float4 v4 = rowp[q];
            float vs[4] = {v4.x, v4.y, v4.z, v4.w};
#pragma unroll
            for (int j = 0; j < 4; j++) {
                const int e = q * 4 + j;
                const float v = vs[j];
                if (v > v0)      { v1 = v0; i1 = i0; v0 = v; i0 = e; }
                else if (v > v1) { v1 = v;  i1 = e; }
            }
        }
        const float e1 = expf(v1 - v0);     // v0 >= v1
        const float w0 = 1.f / (1.f + e1);
        const int tok = tok0 + tid;
        out[tok * 2 + 0] = w0;
        out[tok * 2 + 1] = e1 * w0;
        float* oi = out + (size_t)T * 2;    // indices chunk (float-cast)
        oi[tok * 2 + 0] = (float)i0;
        oi[tok * 2 + 1] = (float)i1;
    }
}

extern "C" void kernel_launch(void* const* d_in, const int* in_sizes, int n_in,
                              void* d_out, int out_size, void* d_ws, size_t ws_size,
                              hipStream_t stream) {
    const float* x = (const float*)d_in[0];
    const float* W = (const float*)d_in[1];
    const float* b = (const float*)d_in[2];
    float* out = (float*)d_out;
    short* wsp = (short*)d_ws;
    const int T = in_sizes[0] / D_MODEL;     // 16384 tokens
    const int grid = T / TPB;                // 512 blocks -> 2 per CU

    const bool pre = (ws_size >= (size_t)(2 * WS_SHORTS) * sizeof(short));  // 1 MB
    if (pre) {
        hipLaunchKernelGGL(wsplit_kernel, dim3(256), dim3(128), 0, stream, W, wsp);
        hipLaunchKernelGGL((router_kernel<true>), dim3(grid), dim3(512), 0, stream,
                           x, W, wsp, b, out, T);
    } else {
        hipLaunchKernelGGL((router_kernel<false>), dim3(grid), dim3(512), 0, stream,
                           x, W, wsp, b, out, T);
    }
}